// Round 3
// baseline (797.019 us; speedup 1.0000x reference)
//
#include <hip/hip_runtime.h>

typedef unsigned short ushort_t;
typedef __attribute__((ext_vector_type(8))) unsigned short ushortx8;
typedef __attribute__((ext_vector_type(8))) __bf16 bf16x8;
typedef __attribute__((ext_vector_type(4))) float floatx4;

// ---------- problem constants ----------
#define NE 8
#define NT 16384
#define ND 1024
#define NF 4096
#define MPE (NT / NE)   // 2048 tokens per expert

// ---------- helpers ----------
__device__ __forceinline__ float b2f(ushort_t x) {
    unsigned u = ((unsigned)x) << 16;
    float f;
    __builtin_memcpy(&f, &u, 4);
    return f;
}
__device__ __forceinline__ ushort_t f2b(float f) {
    unsigned u;
    __builtin_memcpy(&u, &f, 4);
    u += 0x7FFFu + ((u >> 16) & 1u);   // RNE
    return (ushort_t)(u >> 16);
}
// jax.nn.gelu default = tanh approximation
__device__ __forceinline__ float gelu_tanh(float x) {
    float u = x + 0.044715f * x * x * x;
    float e = __expf(1.5957691216f * u);     // exp(2 * sqrt(2/pi) * u)
    float t = 1.0f - 2.0f / (e + 1.0f);      // tanh, inf-safe
    return 0.5f * x * (1.0f + t);
}

// ---------- dtype detector ----------
// If x is fp32-stored, even-index ushorts are low mantissa halves: random bits
// -> ~44% have |bf16| > 1e4 or NaN. Genuine bf16 N(0,1) data: none do.
__global__ void detect_dtype(const ushort_t* __restrict__ x, int* __restrict__ flag) {
    int l = threadIdx.x;                  // 64 threads
    float v = b2f(x[2 * l]);
    float a = fabsf(v);
    int big = (a > 1e4f) || (a != a);
    unsigned long long m = __ballot(big);
    if (l == 0) *flag = (__popcll(m) >= 4) ? 1 : 0;
}

// ---------- convert (fp32|bf16) -> bf16, n multiple of 8 ----------
__global__ __launch_bounds__(256) void conv_bf16(
    const void* __restrict__ src, ushort_t* __restrict__ dst, int n,
    const int* __restrict__ flagp)
{
    int flag = *flagp;
    int i = (blockIdx.x * 256 + threadIdx.x) * 8;
    if (i >= n) return;
    if (flag) {
        const float* s = (const float*)src + i;
        ushortx8 o;
#pragma unroll
        for (int j = 0; j < 8; ++j) o[j] = f2b(s[j]);
        *(ushortx8*)(dst + i) = o;
    } else {
        *(ushortx8*)(dst + i) = *(const ushortx8*)((const ushort_t*)src + i);
    }
}

// ---------- weight transpose (fp32|bf16 src) -> bf16 dst[e][c][r] ----------
// grid (C/64, R/64, E), block 256
__global__ __launch_bounds__(256) void transpose_e(
    const void* __restrict__ src, ushort_t* __restrict__ dst, int R, int C,
    const int* __restrict__ flagp)
{
    __shared__ ushort_t tile[64][72];  // +8 pad: 144B rows, 16B-aligned
    int flag = *flagp;
    int e = blockIdx.z;
    size_t ebase = (size_t)e * R * C;
    int r0 = blockIdx.y * 64, c0 = blockIdx.x * 64;
    int t = threadIdx.x;
#pragma unroll
    for (int i = 0; i < 2; ++i) {
        int ch = t + 256 * i;          // 0..511
        int r = ch >> 3;               // 0..63
        int c = (ch & 7) * 8;
        size_t gi = ebase + (size_t)(r0 + r) * C + (c0 + c);
        ushortx8 v;
        if (flag) {
            const float* s = (const float*)src + gi;
#pragma unroll
            for (int j = 0; j < 8; ++j) v[j] = f2b(s[j]);
        } else {
            v = *(const ushortx8*)((const ushort_t*)src + gi);
        }
        *(ushortx8*)&tile[r][c] = v;
    }
    __syncthreads();
#pragma unroll
    for (int i = 0; i < 2; ++i) {
        int ch = t + 256 * i;
        int oc  = ch >> 3;             // input col = output row
        int orr = (ch & 7) * 8;        // input row octet
        ushortx8 v;
#pragma unroll
        for (int j = 0; j < 8; ++j) v[j] = tile[orr + j][oc];
        *(ushortx8*)(dst + ebase + (size_t)(c0 + oc) * R + (r0 + orr)) = v;
    }
}

// ---------- grouped GEMM:  C[e] = act(A[e] @ Bt[e]^T + bias[e]) ----------
// A: [E*Mpe][K] bf16, Bt: [E][N][K] bf16 (pre-transposed, K-contig), bias bf16.
// DUALOUT: epilogue writes fp32 if *flagp else bf16 (internal H is always bf16).
// grid (N/128, Mpe/128, E), block 256 (4 waves), 128x128x64 tile.
template <int GELU, int DUALOUT>
__global__ __launch_bounds__(256) void gemm_bt(
    const ushort_t* __restrict__ A, const ushort_t* __restrict__ Bt,
    const ushort_t* __restrict__ bias, void* __restrict__ Cout,
    int Mpe, int N, int K, const int* __restrict__ flagp)
{
    constexpr int LDR = 72;  // padded LDS row stride (ushorts)
    __shared__ __align__(16) ushort_t sA[128 * LDR];
    __shared__ __align__(16) ushort_t sB[128 * LDR];

    const int flag = DUALOUT ? *flagp : 0;
    const int e  = blockIdx.z;
    const int m0 = blockIdx.y * 128;
    const int n0 = blockIdx.x * 128;
    const ushort_t* Ae = A  + (size_t)e * Mpe * K + (size_t)m0 * K;
    const ushort_t* Be = Bt + (size_t)e * N   * K + (size_t)n0 * K;

    const int t = threadIdx.x;
    const int w = t >> 6;          // wave 0..3
    const int l = t & 63;
    const int lrow = l >> 3;       // staging: row within 8-row group
    const int lchk = l & 7;        // staging: 16B chunk within 128B row
    const int q  = l >> 4;         // fragment quad
    const int ln = l & 15;         // fragment lane

    floatx4 acc[4][4] = {};

    for (int kt = 0; kt < K; kt += 64) {
        ushortx8 va[4], vb[4];
#pragma unroll
        for (int it = 0; it < 4; ++it) {
            int rb = it * 32 + w * 8 + lrow;
            va[it] = *(const ushortx8*)(Ae + (size_t)rb * K + kt + lchk * 8);
            vb[it] = *(const ushortx8*)(Be + (size_t)rb * K + kt + lchk * 8);
        }
#pragma unroll
        for (int it = 0; it < 4; ++it) {
            int rb = it * 32 + w * 8 + lrow;
            *(ushortx8*)&sA[rb * LDR + lchk * 8] = va[it];
            *(ushortx8*)&sB[rb * LDR + lchk * 8] = vb[it];
        }
        __syncthreads();
#pragma unroll
        for (int ks = 0; ks < 2; ++ks) {
            bf16x8 af[4], bfr[4];
#pragma unroll
            for (int mt = 0; mt < 4; ++mt) {
                int m = (w >> 1) * 64 + mt * 16 + ln;
                af[mt] = *(const bf16x8*)&sA[m * LDR + (ks * 4 + q) * 8];
            }
#pragma unroll
            for (int nt = 0; nt < 4; ++nt) {
                int n = (w & 1) * 64 + nt * 16 + ln;
                bfr[nt] = *(const bf16x8*)&sB[n * LDR + (ks * 4 + q) * 8];
            }
#pragma unroll
            for (int mt = 0; mt < 4; ++mt)
#pragma unroll
                for (int nt = 0; nt < 4; ++nt)
                    acc[mt][nt] = __builtin_amdgcn_mfma_f32_16x16x32_bf16(
                        af[mt], bfr[nt], acc[mt][nt], 0, 0, 0);
        }
        __syncthreads();
    }

    // epilogue: C/D layout col=lane&15, row=quad*4+reg  [m89-verified]
    const ushort_t* be = bias + (size_t)e * N + n0;
#pragma unroll
    for (int nt = 0; nt < 4; ++nt) {
        int col = (w & 1) * 64 + nt * 16 + ln;
        float bv = b2f(be[col]);
#pragma unroll
        for (int mt = 0; mt < 4; ++mt) {
#pragma unroll
            for (int r = 0; r < 4; ++r) {
                int row = (w >> 1) * 64 + mt * 16 + q * 4 + r;
                float v = acc[mt][nt][r] + bv;
                if (GELU) v = gelu_tanh(v);
                size_t idx = (size_t)e * Mpe * N + (size_t)(m0 + row) * N + (n0 + col);
                if (DUALOUT && flag) ((float*)Cout)[idx] = v;
                else                 ((ushort_t*)Cout)[idx] = f2b(v);
            }
        }
    }
}

extern "C" void kernel_launch(void* const* d_in, const int* in_sizes, int n_in,
                              void* d_out, int out_size, void* d_ws, size_t ws_size,
                              hipStream_t stream) {
    const void* x  = d_in[0];
    // d_in[1] = expert_size (uniform T/E by construction, unused)
    const void* w1 = d_in[2];
    const void* b1 = d_in[3];
    const void* w2 = d_in[4];
    const void* b2 = d_in[5];

    char* ws = (char*)d_ws;
    int*      flag = (int*)ws;                                    // @0
    ushort_t* xb   = (ushort_t*)(ws + ((size_t)1  << 20));        // 32 MB
    ushort_t* b1b  = (ushort_t*)(ws + ((size_t)34 << 20));        // 64 KB
    ushort_t* b2b  = (ushort_t*)(ws + ((size_t)35 << 20));        // 16 KB
    ushort_t* wT   = (ushort_t*)(ws + ((size_t)36 << 20));        // 64 MB (w1t, then w2t)
    ushort_t* H    = (ushort_t*)(ws + ((size_t)100 << 20));       // 128 MB -> ends 228 MB

    detect_dtype<<<1, 64, 0, stream>>>((const ushort_t*)x, flag);

    conv_bf16<<<(NT * ND / 8 + 255) / 256, 256, 0, stream>>>(x,  xb,  NT * ND, flag);
    conv_bf16<<<(NE * NF / 8 + 255) / 256, 256, 0, stream>>>(b1, b1b, NE * NF, flag);
    conv_bf16<<<(NE * ND / 8 + 255) / 256, 256, 0, stream>>>(b2, b2b, NE * ND, flag);

    // w1 [E][D][F] -> wT [E][F][D]
    transpose_e<<<dim3(NF / 64, ND / 64, NE), 256, 0, stream>>>(w1, wT, ND, NF, flag);
    // H = gelu(X @ W1 + b1)   (internal, always bf16)
    gemm_bt<1, 0><<<dim3(NF / 128, MPE / 128, NE), 256, 0, stream>>>(
        xb, wT, b1b, H, MPE, NF, ND, flag);
    // w2 [E][F][D] -> wT [E][D][F]   (reuses wT after gemm1 is done)
    transpose_e<<<dim3(ND / 64, NF / 64, NE), 256, 0, stream>>>(w2, wT, NF, ND, flag);
    // Y = H @ W2 + b2   (output dtype follows detected input dtype)
    gemm_bt<0, 1><<<dim3(ND / 128, MPE / 128, NE), 256, 0, stream>>>(
        H, wT, b2b, d_out, MPE, ND, NF, flag);
}

// Round 4
// 795.279 us; speedup vs baseline: 1.0022x; 1.0022x over previous
//
#include <hip/hip_runtime.h>

typedef unsigned short ushort_t;
typedef __attribute__((ext_vector_type(8))) unsigned short ushortx8;
typedef __attribute__((ext_vector_type(8))) __bf16 bf16x8;
typedef __attribute__((ext_vector_type(4))) float floatx4;

// ---------- problem constants ----------
#define NE 8
#define NT 16384
#define ND 1024
#define NF 4096
#define MPE (NT / NE)   // 2048 tokens per expert

// ---------- helpers ----------
__device__ __forceinline__ float b2f(ushort_t x) {
    unsigned u = ((unsigned)x) << 16;
    float f;
    __builtin_memcpy(&f, &u, 4);
    return f;
}
__device__ __forceinline__ ushort_t f2b(float f) {
    unsigned u;
    __builtin_memcpy(&u, &f, 4);
    u += 0x7FFFu + ((u >> 16) & 1u);   // RNE
    return (ushort_t)(u >> 16);
}
// jax.nn.gelu default = tanh approximation
__device__ __forceinline__ float gelu_tanh(float x) {
    float u = x + 0.044715f * x * x * x;
    float e = __expf(1.5957691216f * u);     // exp(2 * sqrt(2/pi) * u)
    float t = 1.0f - 2.0f / (e + 1.0f);      // tanh, inf-safe
    return 0.5f * x * (1.0f + t);
}

// ---------- dtype detector (inputs measured fp32 in round 3; keep robust) ----------
__global__ void detect_dtype(const ushort_t* __restrict__ x, int* __restrict__ flag) {
    int l = threadIdx.x;                  // 64 threads
    float v = b2f(x[2 * l]);
    float a = fabsf(v);
    int big = (a > 1e4f) || (a != a);
    unsigned long long m = __ballot(big);
    if (l == 0) *flag = (__popcll(m) >= 4) ? 1 : 0;
}

// ---------- convert (fp32|bf16) -> bf16, n multiple of 8 ----------
__global__ __launch_bounds__(256) void conv_bf16(
    const void* __restrict__ src, ushort_t* __restrict__ dst, int n,
    const int* __restrict__ flagp)
{
    int flag = *flagp;
    int i = (blockIdx.x * 256 + threadIdx.x) * 8;
    if (i >= n) return;
    if (flag) {
        const float* s = (const float*)src + i;
        ushortx8 o;
#pragma unroll
        for (int j = 0; j < 8; ++j) o[j] = f2b(s[j]);
        *(ushortx8*)(dst + i) = o;
    } else {
        *(ushortx8*)(dst + i) = *(const ushortx8*)((const ushort_t*)src + i);
    }
}

// ---------- weight transpose (fp32|bf16 src) -> bf16 dst[e][c][r] ----------
// grid (C/64, R/64, E), block 256
__global__ __launch_bounds__(256) void transpose_e(
    const void* __restrict__ src, ushort_t* __restrict__ dst, int R, int C,
    const int* __restrict__ flagp)
{
    __shared__ ushort_t tile[64][72];  // +8 pad: 144B rows, 16B-aligned
    int flag = *flagp;
    int e = blockIdx.z;
    size_t ebase = (size_t)e * R * C;
    int r0 = blockIdx.y * 64, c0 = blockIdx.x * 64;
    int t = threadIdx.x;
#pragma unroll
    for (int i = 0; i < 2; ++i) {
        int ch = t + 256 * i;          // 0..511
        int r = ch >> 3;               // 0..63
        int c = (ch & 7) * 8;
        size_t gi = ebase + (size_t)(r0 + r) * C + (c0 + c);
        ushortx8 v;
        if (flag) {
            const float* s = (const float*)src + gi;
#pragma unroll
            for (int j = 0; j < 8; ++j) v[j] = f2b(s[j]);
        } else {
            v = *(const ushortx8*)((const ushort_t*)src + gi);
        }
        *(ushortx8*)&tile[r][c] = v;
    }
    __syncthreads();
#pragma unroll
    for (int i = 0; i < 2; ++i) {
        int ch = t + 256 * i;
        int oc  = ch >> 3;             // input col = output row
        int orr = (ch & 7) * 8;        // input row octet
        ushortx8 v;
#pragma unroll
        for (int j = 0; j < 8; ++j) v[j] = tile[orr + j][oc];
        *(ushortx8*)(dst + ebase + (size_t)(c0 + oc) * R + (r0 + orr)) = v;
    }
}

// ---------- grouped GEMM:  C[e] = act(A[e] @ Bt[e]^T + bias[e]) ----------
// A: [E*Mpe][K] bf16, Bt: [E][N][K] bf16 (pre-transposed, K-contig), bias bf16.
// Staging: global_load_lds width=16 (m97 recipe). LDS dest is forced to
// base + lane*16, so the *global* lane->chunk map carries an XOR swizzle:
// logical 16B-chunk c of row m lands at phys chunk c^(m&7). Fragment reads
// then hit 8 distinct 4-bank groups with 2 lanes each (free, m136).
// DUALOUT: epilogue writes fp32 if *flagp else bf16 (internal H always bf16).
// grid (N/128, Mpe/128, E), block 256 (4 waves), 128x128x64 tile.
template <int GELU, int DUALOUT>
__global__ __launch_bounds__(256) void gemm_bt(
    const ushort_t* __restrict__ A, const ushort_t* __restrict__ Bt,
    const ushort_t* __restrict__ bias, void* __restrict__ Cout,
    int Mpe, int N, int K, const int* __restrict__ flagp)
{
    __shared__ __align__(16) ushort_t sA[128 * 64];
    __shared__ __align__(16) ushort_t sB[128 * 64];

    const int flag = DUALOUT ? *flagp : 0;
    const int e  = blockIdx.z;
    const int m0 = blockIdx.y * 128;
    const int n0 = blockIdx.x * 128;
    const ushort_t* Ae = A  + (size_t)e * Mpe * K + (size_t)m0 * K;
    const ushort_t* Be = Bt + (size_t)e * N   * K + (size_t)n0 * K;

    const int t = threadIdx.x;
    const int w = t >> 6;          // wave 0..3
    const int l = t & 63;
    // staging lane roles: 8 rows x 8 chunks(16B) per instruction
    const int lwr = l >> 3;        // row within the 8-row group
    const int swz = (l & 7) ^ lwr; // this lane fetches logical chunk swz
    // fragment lane roles
    const int q  = l >> 4;         // 0..3
    const int ln = l & 15;

    floatx4 acc[4][4] = {};

    for (int kt = 0; kt < K; kt += 64) {
#pragma unroll
        for (int it = 0; it < 4; ++it) {
            int rb = it * 32 + w * 8;  // wave-uniform 8-row block
            const ushort_t* ga = Ae + (size_t)(rb + lwr) * K + kt + swz * 8;
            __builtin_amdgcn_global_load_lds(
                (const __attribute__((address_space(1))) void*)ga,
                (__attribute__((address_space(3))) void*)&sA[rb * 64], 16, 0, 0);
            const ushort_t* gb = Be + (size_t)(rb + lwr) * K + kt + swz * 8;
            __builtin_amdgcn_global_load_lds(
                (const __attribute__((address_space(1))) void*)gb,
                (__attribute__((address_space(3))) void*)&sB[rb * 64], 16, 0, 0);
        }
        __syncthreads();
#pragma unroll
        for (int ks = 0; ks < 2; ++ks) {
            bf16x8 af[4], bfr[4];
#pragma unroll
            for (int mt = 0; mt < 4; ++mt) {
                int m = (w >> 1) * 64 + mt * 16 + ln;
                af[mt] = *(const bf16x8*)&sA[m * 64 + (((ks * 4 + q) ^ (m & 7)) * 8)];
            }
#pragma unroll
            for (int nt = 0; nt < 4; ++nt) {
                int n = (w & 1) * 64 + nt * 16 + ln;
                bfr[nt] = *(const bf16x8*)&sB[n * 64 + (((ks * 4 + q) ^ (n & 7)) * 8)];
            }
#pragma unroll
            for (int mt = 0; mt < 4; ++mt)
#pragma unroll
                for (int nt = 0; nt < 4; ++nt)
                    acc[mt][nt] = __builtin_amdgcn_mfma_f32_16x16x32_bf16(
                        af[mt], bfr[nt], acc[mt][nt], 0, 0, 0);
        }
        __syncthreads();
    }

    // epilogue: C/D layout col=lane&15, row=quad*4+reg  [m89-verified]
    const ushort_t* be = bias + (size_t)e * N + n0;
#pragma unroll
    for (int nt = 0; nt < 4; ++nt) {
        int col = (w & 1) * 64 + nt * 16 + ln;
        float bv = b2f(be[col]);
#pragma unroll
        for (int mt = 0; mt < 4; ++mt) {
#pragma unroll
            for (int r = 0; r < 4; ++r) {
                int row = (w >> 1) * 64 + mt * 16 + q * 4 + r;
                float v = acc[mt][nt][r] + bv;
                if (GELU) v = gelu_tanh(v);
                size_t idx = (size_t)e * Mpe * N + (size_t)(m0 + row) * N + (n0 + col);
                if (DUALOUT && flag) ((float*)Cout)[idx] = v;
                else                 ((ushort_t*)Cout)[idx] = f2b(v);
            }
        }
    }
}

extern "C" void kernel_launch(void* const* d_in, const int* in_sizes, int n_in,
                              void* d_out, int out_size, void* d_ws, size_t ws_size,
                              hipStream_t stream) {
    const void* x  = d_in[0];
    // d_in[1] = expert_size (uniform T/E by construction, unused)
    const void* w1 = d_in[2];
    const void* b1 = d_in[3];
    const void* w2 = d_in[4];
    const void* b2 = d_in[5];

    char* ws = (char*)d_ws;
    int*      flag = (int*)ws;                                    // @0
    ushort_t* xb   = (ushort_t*)(ws + ((size_t)1  << 20));        // 32 MB
    ushort_t* b1b  = (ushort_t*)(ws + ((size_t)34 << 20));        // 64 KB
    ushort_t* b2b  = (ushort_t*)(ws + ((size_t)35 << 20));        // 16 KB
    ushort_t* wT   = (ushort_t*)(ws + ((size_t)36 << 20));        // 64 MB (w1t, then w2t)
    ushort_t* H    = (ushort_t*)(ws + ((size_t)100 << 20));       // 128 MB -> ends 228 MB

    detect_dtype<<<1, 64, 0, stream>>>((const ushort_t*)x, flag);

    conv_bf16<<<(NT * ND / 8 + 255) / 256, 256, 0, stream>>>(x,  xb,  NT * ND, flag);
    conv_bf16<<<(NE * NF / 8 + 255) / 256, 256, 0, stream>>>(b1, b1b, NE * NF, flag);
    conv_bf16<<<(NE * ND / 8 + 255) / 256, 256, 0, stream>>>(b2, b2b, NE * ND, flag);

    // w1 [E][D][F] -> wT [E][F][D]
    transpose_e<<<dim3(NF / 64, ND / 64, NE), 256, 0, stream>>>(w1, wT, ND, NF, flag);
    // H = gelu(X @ W1 + b1)   (internal, always bf16)
    gemm_bt<1, 0><<<dim3(NF / 128, MPE / 128, NE), 256, 0, stream>>>(
        xb, wT, b1b, H, MPE, NF, ND, flag);
    // w2 [E][F][D] -> wT [E][D][F]   (reuses wT after gemm1 is done)
    transpose_e<<<dim3(ND / 64, NF / 64, NE), 256, 0, stream>>>(w2, wT, NF, ND, flag);
    // Y = H @ W2 + b2   (output dtype follows detected input dtype)
    gemm_bt<0, 1><<<dim3(ND / 128, MPE / 128, NE), 256, 0, stream>>>(
        H, wT, b2b, d_out, MPE, ND, NF, flag);
}